// Round 1
// baseline (216.000 us; speedup 1.0000x reference)
//
#include <hip/hip_runtime.h>
#include <math.h>

// Problem constants (B=2, C=128, N=256, H=64, CH=256)
#define BB 2
#define CC 128
#define NN 256
#define HH 64
#define CHX 256
#define COLS 768           // 3*N flattened (v,n) columns
#define NEG_ATTN 0.2f
#define NEG_FFN 0.1f

// ---------------------------------------------------------------------------
// K1: q,k,v = Wq/Wk/Wv @ x, written in three layouts:
//   q_t[b][n][c][3]   (per-row fetch in attention)
//   k_nat[b][c][3][n] (coalesced over j in phase 1)
//   v_t[b][n][3][c]   (coalesced over c in PV)
// grid (24 col-tiles, 3 which, B), 256 threads
// ---------------------------------------------------------------------------
__global__ __launch_bounds__(256) void k_qkv(
    const float* __restrict__ x, const float* __restrict__ Wq,
    const float* __restrict__ Wk, const float* __restrict__ Wv,
    float* __restrict__ q_t, float* __restrict__ k_nat, float* __restrict__ v_t)
{
  const int ct = blockIdx.x, which = blockIdx.y, b = blockIdx.z;
  const int col0 = ct * 32;
  __shared__ float xt[128][32];
  const float* xb = x + (size_t)b * CC * COLS;
  for (int idx = threadIdx.x; idx < 128 * 32; idx += 256) {
    int r = idx >> 5, cc = idx & 31;
    xt[r][cc] = xb[r * COLS + col0 + cc];
  }
  __syncthreads();
  const float* W = (which == 0) ? Wq : ((which == 1) ? Wk : Wv);
  const int co = threadIdx.x >> 1;
  const int cc0 = (threadIdx.x & 1) * 16;
  float acc[16];
#pragma unroll
  for (int k = 0; k < 16; k++) acc[k] = 0.f;
  const float* wrow = W + co * CC;
  for (int ci = 0; ci < CC; ci++) {
    float wv = wrow[ci];
#pragma unroll
    for (int k = 0; k < 16; k++) acc[k] = fmaf(wv, xt[ci][cc0 + k], acc[k]);
  }
#pragma unroll
  for (int k = 0; k < 16; k++) {
    int col = col0 + cc0 + k;
    int v = col >> 8, n = col & 255;
    float val = acc[k];
    if (which == 0)      q_t[((size_t)(b * NN + n) * CC + co) * 3 + v] = val;
    else if (which == 1) k_nat[(size_t)(b * CC + co) * COLS + col] = val;
    else                 v_t[((size_t)(b * NN + n) * 3 + v) * CC + co] = val;
  }
}

// ---------------------------------------------------------------------------
// K2: fused attention per (b,i): rel_mean/rel_pos -> score MLP -> online
// softmax over j -> PV.  grid (N, B), 256 threads.
// Thread roles: phase1 t=j; phase2 (jl = t&127, h-range by t>>7);
// phase3 (c = t&127, j-parity = t>>7).
// ---------------------------------------------------------------------------
__global__ __launch_bounds__(256) void k_attn(
    const float* __restrict__ q_t, const float* __restrict__ k_nat,
    const float* __restrict__ v_t, const float* __restrict__ pos,
    const float* __restrict__ W1, const float* __restrict__ b1,
    const float* __restrict__ W2, const float* __restrict__ b2,
    float* __restrict__ a_nat)
{
  const int i = blockIdx.x, b = blockIdx.y;
  const int t = threadIdx.x;

  __shared__ float qv[CC * 3];
  __shared__ float rm_s[NN], rp_s[NN];
  __shared__ float W1s[2 * HH], b1s[HH];
  __shared__ __align__(16) float hh_s[128][HH];  // 32 KB, one j-half at a time
  __shared__ float mrg[128][6];

  for (int idx = t; idx < CC * 3; idx += 256) qv[idx] = q_t[(size_t)(b * NN + i) * CC * 3 + idx];
  for (int idx = t; idx < 2 * HH; idx += 256) W1s[idx] = W1[idx];
  for (int idx = t; idx < HH; idx += 256) b1s[idx] = b1[idx];
  const float pix = pos[(b * NN + i) * 3 + 0];
  const float piy = pos[(b * NN + i) * 3 + 1];
  const float piz = pos[(b * NN + i) * 3 + 2];
  __syncthreads();

  // ---- phase 1: rm[j], rp[j]  (thread t == j) ----
  {
    const int j = t;
    const float* kb = k_nat + (size_t)b * CC * COLS;
    float accn = 0.f;
    for (int c = 0; c < CC; c++) {
      float dx = kb[c * COLS + j]       - qv[c * 3 + 0];
      float dy = kb[c * COLS + 256 + j] - qv[c * 3 + 1];
      float dz = kb[c * COLS + 512 + j] - qv[c * 3 + 2];
      float sq = dx * dx + dy * dy + dz * dz;
      accn += (sq > 0.f) ? sqrtf(sq) : 0.f;
    }
    rm_s[j] = accn * (1.f / 128.f);
    float px = pos[(b * NN + j) * 3 + 0] - pix;
    float py = pos[(b * NN + j) * 3 + 1] - piy;
    float pz = pos[(b * NN + j) * 3 + 2] - piz;
    float sq = px * px + py * py + pz * pz;
    rp_s[j] = (sq > 0.f) ? sqrtf(sq) : 0.f;
  }
  __syncthreads();

  // W2 row for this thread's channel, kept in registers
  const int c = t & 127, par = t >> 7;
  float4 w2r[16];
  {
    const float4* wp = reinterpret_cast<const float4*>(W2 + c * HH);
#pragma unroll
    for (int k = 0; k < 16; k++) w2r[k] = wp[k];
  }
  const float b2c = b2[c];

  float m = -1e30f, l = 0.f, a0 = 0.f, a1 = 0.f, a2 = 0.f;

  for (int half = 0; half < 2; half++) {
    // ---- phase 2: h-tile for j in [half*128, half*128+128) ----
    {
      const int jl = t & 127;
      const int j = half * 128 + jl;
      const int h0 = (t >> 7) * 32;
      const float rmv = rm_s[j], rpv = rp_s[j];
      for (int hq = h0; hq < h0 + 32; hq++) {
        float g = fmaf(W1s[2 * hq], rmv, fmaf(W1s[2 * hq + 1], rpv, b1s[hq]));
        hh_s[jl][hq] = (g >= 0.f) ? g : NEG_ATTN * g;
      }
    }
    __syncthreads();

    // ---- phase 3: scores + online softmax + PV ----
    for (int jj = 0; jj < 64; jj++) {
      const int jl = jj * 2 + par;
      const int j = half * 128 + jl;
      const float4* hp = reinterpret_cast<const float4*>(hh_s[jl]);
      float s = b2c;
#pragma unroll
      for (int k = 0; k < 16; k++) {
        float4 h4 = hp[k];
        s = fmaf(w2r[k].x, h4.x, s);
        s = fmaf(w2r[k].y, h4.y, s);
        s = fmaf(w2r[k].z, h4.z, s);
        s = fmaf(w2r[k].w, h4.w, s);
      }
      float mn = fmaxf(m, s);
      float p = __expf(s - mn);
      float corr = __expf(m - mn);
      const float* vb = v_t + ((size_t)(b * NN + j) * 3) * CC + c;
      l = fmaf(l, corr, p);
      a0 = fmaf(a0, corr, p * vb[0]);
      a1 = fmaf(a1, corr, p * vb[CC]);
      a2 = fmaf(a2, corr, p * vb[2 * CC]);
      m = mn;
    }
    __syncthreads();
  }

  // ---- merge the two j-parities per channel ----
  if (par == 1) {
    mrg[c][0] = m; mrg[c][1] = l; mrg[c][2] = a0; mrg[c][3] = a1; mrg[c][4] = a2;
  }
  __syncthreads();
  if (par == 0) {
    float m2 = mrg[c][0], l2 = mrg[c][1];
    float mn = fmaxf(m, m2);
    float s1 = __expf(m - mn), s2 = __expf(m2 - mn);
    float L = l * s1 + l2 * s2;
    float inv = 1.f / L;
    float o0 = (a0 * s1 + mrg[c][2] * s2) * inv;
    float o1 = (a1 * s1 + mrg[c][3] * s2) * inv;
    float o2 = (a2 * s1 + mrg[c][4] * s2) * inv;
    float* ap = a_nat + (size_t)(b * CC + c) * COLS + i;
    ap[0] = o0; ap[256] = o1; ap[512] = o2;
  }
}

// ---------------------------------------------------------------------------
// K3: y1 = x + Wo @ a_nat.  grid (24, B), 256 threads.
// ---------------------------------------------------------------------------
__global__ __launch_bounds__(256) void k_wo_res(
    const float* __restrict__ a_nat, const float* __restrict__ Wo,
    const float* __restrict__ x, float* __restrict__ y1)
{
  const int ct = blockIdx.x, b = blockIdx.y;
  const int col0 = ct * 32;
  __shared__ float at[128][32];
  const float* ab = a_nat + (size_t)b * CC * COLS;
  for (int idx = threadIdx.x; idx < 128 * 32; idx += 256) {
    int r = idx >> 5, cc = idx & 31;
    at[r][cc] = ab[r * COLS + col0 + cc];
  }
  __syncthreads();
  const int co = threadIdx.x >> 1;
  const int cc0 = (threadIdx.x & 1) * 16;
  float acc[16];
#pragma unroll
  for (int k = 0; k < 16; k++) acc[k] = 0.f;
  const float* wrow = Wo + co * CC;
  for (int ci = 0; ci < CC; ci++) {
    float wv = wrow[ci];
#pragma unroll
    for (int k = 0; k < 16; k++) acc[k] = fmaf(wv, at[ci][cc0 + k], acc[k]);
  }
  const size_t base = (size_t)(b * CC + co) * COLS + col0 + cc0;
#pragma unroll
  for (int k = 0; k < 16; k++) y1[base + k] = x[base + k] + acc[k];
}

// ---------------------------------------------------------------------------
// K4: ZCA stats + 3x3 Jacobi eigh + whitening matrix. 1 block per batch.
// stats[b*12 + 0..2] = mu, stats[b*12 + 3..11] = Wm row-major.
// ---------------------------------------------------------------------------
__global__ __launch_bounds__(1024) void k_zca_stats(
    const float* __restrict__ y, float* __restrict__ stats)
{
  const int b = blockIdx.x;
  const float* yb = y + (size_t)b * CC * COLS;
  float v9[9];
#pragma unroll
  for (int k = 0; k < 9; k++) v9[k] = 0.f;
  for (int idx = threadIdx.x; idx < CC * NN; idx += 1024) {
    int cidx = idx >> 8, n = idx & 255;
    const float* row = yb + cidx * COLS + n;
    float v0 = row[0], v1 = row[256], v2 = row[512];
    v9[0] += v0; v9[1] += v1; v9[2] += v2;
    v9[3] += v0 * v0; v9[4] += v0 * v1; v9[5] += v0 * v2;
    v9[6] += v1 * v1; v9[7] += v1 * v2; v9[8] += v2 * v2;
  }
#pragma unroll
  for (int off = 32; off >= 1; off >>= 1)
#pragma unroll
    for (int k = 0; k < 9; k++) v9[k] += __shfl_down(v9[k], off);
  __shared__ float red[16][9];
  const int wid = threadIdx.x >> 6, lane = threadIdx.x & 63;
  if (lane == 0)
#pragma unroll
    for (int k = 0; k < 9; k++) red[wid][k] = v9[k];
  __syncthreads();
  if (threadIdx.x == 0) {
    float tot[9];
#pragma unroll
    for (int k = 0; k < 9; k++) tot[k] = 0.f;
    for (int w = 0; w < 16; w++)
#pragma unroll
      for (int k = 0; k < 9; k++) tot[k] += red[w][k];
    const float M = (float)(CC * NN);
    float mu0 = tot[0] / M, mu1 = tot[1] / M, mu2 = tot[2] / M;
    float A[3][3];
    A[0][0] = (tot[3] - M * mu0 * mu0) / M + 1e-5f;
    A[0][1] = A[1][0] = (tot[4] - M * mu0 * mu1) / M;
    A[0][2] = A[2][0] = (tot[5] - M * mu0 * mu2) / M;
    A[1][1] = (tot[6] - M * mu1 * mu1) / M + 1e-5f;
    A[1][2] = A[2][1] = (tot[7] - M * mu1 * mu2) / M;
    A[2][2] = (tot[8] - M * mu2 * mu2) / M + 1e-5f;
    // Jacobi eigendecomposition, V columns = eigenvectors
    float V[3][3] = {{1.f, 0.f, 0.f}, {0.f, 1.f, 0.f}, {0.f, 0.f, 1.f}};
    for (int sweep = 0; sweep < 12; sweep++) {
      for (int pi = 0; pi < 3; pi++) {
        const int p = (pi == 2) ? 1 : 0;
        const int q = (pi == 0) ? 1 : 2;
        float apq = A[p][q];
        if (fabsf(apq) < 1e-30f) continue;
        float theta = (A[q][q] - A[p][p]) / (2.f * apq);
        float tt = 1.f / (fabsf(theta) + sqrtf(theta * theta + 1.f));
        if (theta < 0.f) tt = -tt;
        float cr = 1.f / sqrtf(tt * tt + 1.f);
        float sr = tt * cr;
        float app = A[p][p], aqq = A[q][q];
        A[p][p] = app - tt * apq;
        A[q][q] = aqq + tt * apq;
        A[p][q] = A[q][p] = 0.f;
        const int r = 3 - p - q;
        float arp = A[r][p], arq = A[r][q];
        A[r][p] = A[p][r] = cr * arp - sr * arq;
        A[r][q] = A[q][r] = sr * arp + cr * arq;
        for (int rr = 0; rr < 3; rr++) {
          float vrp = V[rr][p], vrq = V[rr][q];
          V[rr][p] = cr * vrp - sr * vrq;
          V[rr][q] = sr * vrp + cr * vrq;
        }
      }
    }
    float rs[3];
#pragma unroll
    for (int k = 0; k < 3; k++) rs[k] = rsqrtf(fmaxf(A[k][k], 1e-5f));
    float* st = stats + b * 12;
    st[0] = mu0; st[1] = mu1; st[2] = mu2;
    for (int u = 0; u < 3; u++)
      for (int v = 0; v < 3; v++) {
        float acc = 0.f;
        for (int k = 0; k < 3; k++) acc += V[u][k] * rs[k] * V[v][k];
        st[3 + u * 3 + v] = acc;
      }
  }
}

// ---------------------------------------------------------------------------
// K5: apply whitening: out[b,c,v,n] = gamma[c] * sum_u Wm[v][u]*(y - mu)
// ---------------------------------------------------------------------------
__global__ __launch_bounds__(256) void k_zca_apply(
    const float* __restrict__ y, const float* __restrict__ stats,
    const float* __restrict__ gamma, float* __restrict__ out)
{
  const int total = BB * CC * NN;
  for (int idx = blockIdx.x * blockDim.x + threadIdx.x; idx < total;
       idx += gridDim.x * blockDim.x) {
    int b = idx >> 15, rem = idx & 32767;
    int cidx = rem >> 8, n = rem & 255;
    const float* st = stats + b * 12;
    const size_t base = (size_t)(b * CC + cidx) * COLS + n;
    float v0 = y[base] - st[0];
    float v1 = y[base + 256] - st[1];
    float v2 = y[base + 512] - st[2];
    float g = gamma[cidx];
    out[base]       = g * (st[3] * v0 + st[4] * v1 + st[5] * v2);
    out[base + 256] = g * (st[6] * v0 + st[7] * v1 + st[8] * v2);
    out[base + 512] = g * (st[9] * v0 + st[10] * v1 + st[11] * v2);
  }
}

// ---------------------------------------------------------------------------
// K6: FFN part 1: h = vn_leaky_relu(Wfeat@x1, Wdir@x1), fused.
// grid (8 n-tiles, 4 co-splits, B), 256 threads.
// ---------------------------------------------------------------------------
__global__ __launch_bounds__(256) void k_ffn1(
    const float* __restrict__ x1, const float* __restrict__ Wfeat,
    const float* __restrict__ Wdir, float* __restrict__ hout)
{
  const int nt = blockIdx.x, cs = blockIdx.y, b = blockIdx.z;
  const int n0 = nt * 32, co0 = cs * 64;
  __shared__ float xt[128][96];  // [ci][v*32+nn]
  const float* xb = x1 + (size_t)b * CC * COLS;
  for (int idx = threadIdx.x; idx < 128 * 96; idx += 256) {
    int ci = idx / 96, col = idx - ci * 96;
    int v = col >> 5, nn = col & 31;
    xt[ci][col] = xb[ci * COLS + v * 256 + n0 + nn];
  }
  __syncthreads();
  const int co = co0 + (threadIdx.x & 63);
  const int nn0 = (threadIdx.x >> 6) * 8;
  float p[3][8], d[3][8];
#pragma unroll
  for (int v = 0; v < 3; v++)
#pragma unroll
    for (int k = 0; k < 8; k++) { p[v][k] = 0.f; d[v][k] = 0.f; }
  const float* wf = Wfeat + co * CC;
  const float* wd = Wdir + co * CC;
  for (int ci = 0; ci < CC; ci++) {
    float a = wf[ci], bb = wd[ci];
#pragma unroll
    for (int v = 0; v < 3; v++)
#pragma unroll
      for (int k = 0; k < 8; k++) {
        float xv = xt[ci][v * 32 + nn0 + k];
        p[v][k] = fmaf(a, xv, p[v][k]);
        d[v][k] = fmaf(bb, xv, d[v][k]);
      }
  }
  float* hb = hout + (size_t)(b * CHX + co) * COLS;
#pragma unroll
  for (int k = 0; k < 8; k++) {
    float dot = p[0][k] * d[0][k] + p[1][k] * d[1][k] + p[2][k] * d[2][k];
    float dsq = d[0][k] * d[0][k] + d[1][k] * d[1][k] + d[2][k] * d[2][k];
    float coef = (dot >= 0.f) ? 0.f : (1.f - NEG_FFN) * dot / (dsq + 1e-6f);
#pragma unroll
    for (int v = 0; v < 3; v++)
      hb[v * 256 + n0 + nn0 + k] = p[v][k] - coef * d[v][k];
  }
}

// ---------------------------------------------------------------------------
// K7: x2 = x1 + Wffn2 @ h.  grid (24, B), 256 threads.
// ---------------------------------------------------------------------------
__global__ __launch_bounds__(256) void k_ffn2(
    const float* __restrict__ h, const float* __restrict__ Wffn2,
    const float* __restrict__ x1, float* __restrict__ x2)
{
  const int ct = blockIdx.x, b = blockIdx.y;
  const int col0 = ct * 32;
  __shared__ float ht[256][32];
  const float* hb = h + (size_t)b * CHX * COLS;
  for (int idx = threadIdx.x; idx < 256 * 32; idx += 256) {
    int r = idx >> 5, cc = idx & 31;
    ht[r][cc] = hb[r * COLS + col0 + cc];
  }
  __syncthreads();
  const int co = threadIdx.x >> 1;
  const int cc0 = (threadIdx.x & 1) * 16;
  float acc[16];
#pragma unroll
  for (int k = 0; k < 16; k++) acc[k] = 0.f;
  const float* w = Wffn2 + co * CHX;
  for (int ci = 0; ci < CHX; ci++) {
    float wv = w[ci];
#pragma unroll
    for (int k = 0; k < 16; k++) acc[k] = fmaf(wv, ht[ci][cc0 + k], acc[k]);
  }
  const size_t base = (size_t)(b * CC + co) * COLS + col0 + cc0;
#pragma unroll
  for (int k = 0; k < 16; k++) x2[base + k] = x1[base + k] + acc[k];
}

// ---------------------------------------------------------------------------
extern "C" void kernel_launch(void* const* d_in, const int* in_sizes, int n_in,
                              void* d_out, int out_size, void* d_ws, size_t ws_size,
                              hipStream_t stream)
{
  (void)in_sizes; (void)n_in; (void)out_size; (void)ws_size;
  const float* x      = (const float*)d_in[0];
  const float* pos    = (const float*)d_in[1];
  const float* Wq     = (const float*)d_in[2];
  const float* Wk     = (const float*)d_in[3];
  const float* Wv     = (const float*)d_in[4];
  const float* Wo     = (const float*)d_in[5];
  const float* W1     = (const float*)d_in[6];
  const float* b1     = (const float*)d_in[7];
  const float* W2     = (const float*)d_in[8];
  const float* b2     = (const float*)d_in[9];
  const float* gamma1 = (const float*)d_in[10];
  const float* Wfeat  = (const float*)d_in[11];
  const float* Wdir   = (const float*)d_in[12];
  const float* Wffn2  = (const float*)d_in[13];
  const float* gamma2 = (const float*)d_in[14];

  float* ws = (float*)d_ws;
  const size_t SZ = (size_t)BB * CC * 3 * NN;  // 393216
  float* q_t   = ws;            // [0, SZ)
  float* k_nat = ws + SZ;       // [SZ, 2SZ)
  float* v_t   = ws + 2 * SZ;   // [2SZ, 3SZ)
  float* a_nat = ws + 3 * SZ;   // [3SZ, 4SZ)
  float* y1    = ws;            // alias q_t (dead after k_attn)
  float* x1    = ws + SZ;       // alias k_nat (dead after k_attn)
  float* hbuf  = ws + 2 * SZ;   // alias v_t + a_nat (dead), size 2*SZ
  float* x2    = ws;            // alias y1 (dead after first apply)
  float* stats = ws + 4 * SZ;   // 2*12 floats

  k_qkv<<<dim3(24, 3, BB), 256, 0, stream>>>(x, Wq, Wk, Wv, q_t, k_nat, v_t);
  k_attn<<<dim3(NN, BB), 256, 0, stream>>>(q_t, k_nat, v_t, pos, W1, b1, W2, b2, a_nat);
  k_wo_res<<<dim3(24, BB), 256, 0, stream>>>(a_nat, Wo, x, y1);
  k_zca_stats<<<BB, 1024, 0, stream>>>(y1, stats);
  k_zca_apply<<<256, 256, 0, stream>>>(y1, stats, gamma1, x1);
  k_ffn1<<<dim3(8, 4, BB), 256, 0, stream>>>(x1, Wfeat, Wdir, hbuf);
  k_ffn2<<<dim3(24, BB), 256, 0, stream>>>(hbuf, Wffn2, x1, x2);
  k_zca_stats<<<BB, 1024, 0, stream>>>(x2, stats + 32);
  k_zca_apply<<<256, 256, 0, stream>>>(x2, stats + 32, gamma2, (float*)d_out);
}

// Round 2
// 150.485 us; speedup vs baseline: 1.4354x; 1.4354x over previous
//
#include <hip/hip_runtime.h>
#include <math.h>

// Problem constants (B=2, C=128, N=256, H=64, CH=256)
#define BB 2
#define CC 128
#define NN 256
#define HH 64
#define CHX 256
#define COLS 768           // 3*N flattened (v,n) columns
#define NEG_ATTN 0.2f
#define NEG_FFN 0.1f

// ---------------------------------------------------------------------------
// K1: q,k,v = Wq/Wk/Wv @ x in three layouts.
// grid (48 col-tiles of 16, 3 which, B), 256 threads
// ---------------------------------------------------------------------------
__global__ __launch_bounds__(256) void k_qkv(
    const float* __restrict__ x, const float* __restrict__ Wq,
    const float* __restrict__ Wk, const float* __restrict__ Wv,
    float* __restrict__ q_t, float* __restrict__ k_nat, float* __restrict__ v_t)
{
  const int ct = blockIdx.x, which = blockIdx.y, b = blockIdx.z;
  const int col0 = ct * 16;
  __shared__ float xt[CC][16];
  const float* xb = x + (size_t)b * CC * COLS;
  for (int idx = threadIdx.x; idx < CC * 16; idx += 256) {
    int r = idx >> 4, cc = idx & 15;
    xt[r][cc] = xb[r * COLS + col0 + cc];
  }
  __syncthreads();
  const float* W = (which == 0) ? Wq : ((which == 1) ? Wk : Wv);
  const int co = threadIdx.x >> 1;
  const int cc0 = (threadIdx.x & 1) * 8;
  float acc[8];
#pragma unroll
  for (int k = 0; k < 8; k++) acc[k] = 0.f;
  const float* wrow = W + co * CC;
  for (int ci = 0; ci < CC; ci++) {
    float wv = wrow[ci];
#pragma unroll
    for (int k = 0; k < 8; k++) acc[k] = fmaf(wv, xt[ci][cc0 + k], acc[k]);
  }
#pragma unroll
  for (int k = 0; k < 8; k++) {
    int col = col0 + cc0 + k;
    int v = col >> 8, n = col & 255;
    float val = acc[k];
    if (which == 0)      q_t[((size_t)(b * NN + n) * CC + co) * 3 + v] = val;
    else if (which == 1) k_nat[(size_t)(b * CC + co) * COLS + col] = val;
    else                 v_t[((size_t)(b * NN + n) * 3 + v) * CC + co] = val;
  }
}

// ---------------------------------------------------------------------------
// K2: fused attention per (b, i, c-half). grid (N, 2, B) = 1024 blocks, 256 thr.
// phase1: t=j computes rm/rp; phase2: lane=h conflict-free hh writes;
// phase3: c = chalf*64 + (t&63), j-quarter = t>>6.
// ---------------------------------------------------------------------------
__global__ __launch_bounds__(256, 4) void k_attn(
    const float* __restrict__ q_t, const float* __restrict__ k_nat,
    const float* __restrict__ v_t, const float* __restrict__ pos,
    const float* __restrict__ W1, const float* __restrict__ b1,
    const float* __restrict__ W2, const float* __restrict__ b2,
    float* __restrict__ a_nat)
{
  const int i = blockIdx.x, chalf = blockIdx.y, b = blockIdx.z;
  const int t = threadIdx.x;

  __shared__ float qv[CC * 3];
  __shared__ float rm_s[NN], rp_s[NN];
  __shared__ float W1s[2 * HH], b1s[HH];
  __shared__ __align__(16) float hh_s[128][HH];  // 32 KB, one j-half at a time
  float* mrg = (float*)hh_s;                      // aliased: used only after last phase 3

  for (int idx = t; idx < CC * 3; idx += 256) qv[idx] = q_t[(size_t)(b * NN + i) * CC * 3 + idx];
  for (int idx = t; idx < 2 * HH; idx += 256) W1s[idx] = W1[idx];
  for (int idx = t; idx < HH; idx += 256) b1s[idx] = b1[idx];
  const float pix = pos[(b * NN + i) * 3 + 0];
  const float piy = pos[(b * NN + i) * 3 + 1];
  const float piz = pos[(b * NN + i) * 3 + 2];
  __syncthreads();

  // ---- phase 1: rm[j], rp[j]  (thread t == j), 4 independent partials ----
  {
    const int j = t;
    const float* kb = k_nat + (size_t)b * CC * COLS;
    float p0 = 0.f, p1 = 0.f, p2 = 0.f, p3 = 0.f;
    for (int c = 0; c < CC; c += 4) {
#pragma unroll
      for (int u = 0; u < 4; u++) {
        const int cu = c + u;
        float dx = kb[cu * COLS + j]       - qv[cu * 3 + 0];
        float dy = kb[cu * COLS + 256 + j] - qv[cu * 3 + 1];
        float dz = kb[cu * COLS + 512 + j] - qv[cu * 3 + 2];
        float sq = dx * dx + dy * dy + dz * dz;
        float r = (sq > 0.f) ? sqrtf(sq) : 0.f;
        if (u == 0) p0 += r; else if (u == 1) p1 += r; else if (u == 2) p2 += r; else p3 += r;
      }
    }
    rm_s[j] = ((p0 + p1) + (p2 + p3)) * (1.f / 128.f);
    float px = pos[(b * NN + j) * 3 + 0] - pix;
    float py = pos[(b * NN + j) * 3 + 1] - piy;
    float pz = pos[(b * NN + j) * 3 + 2] - piz;
    float sq = px * px + py * py + pz * pz;
    rp_s[j] = (sq > 0.f) ? sqrtf(sq) : 0.f;
  }
  __syncthreads();

  // W2 row for this thread's channel, kept in registers (128-VGPR budget)
  const int cl = t & 63, par = t >> 6;
  const int c = chalf * 64 + cl;
  float4 w2r[16];
  {
    const float4* wp = reinterpret_cast<const float4*>(W2 + c * HH);
#pragma unroll
    for (int k = 0; k < 16; k++) w2r[k] = wp[k];
  }
  const float b2c = b2[c];

  float m = -1e30f, l = 0.f, a0 = 0.f, a1 = 0.f, a2 = 0.f;

  for (int half = 0; half < 2; half++) {
    // ---- phase 2: hh for j-half; lane = h (conflict-free column writes) ----
    {
      const int h = t & 63;
      const int jg = t >> 6;
      const float wa = W1s[2 * h], wb = W1s[2 * h + 1], bb1 = b1s[h];
      for (int jl = jg * 32; jl < jg * 32 + 32; jl++) {
        const int j = half * 128 + jl;
        float g = fmaf(wa, rm_s[j], fmaf(wb, rp_s[j], bb1));
        hh_s[jl][h] = (g >= 0.f) ? g : NEG_ATTN * g;
      }
    }
    __syncthreads();

    // ---- phase 3: scores + online softmax + PV (64 j per thread) ----
    for (int jj = 0; jj < 32; jj++) {
      const int jl = jj * 4 + par;
      const int j = half * 128 + jl;
      const float4* hp = reinterpret_cast<const float4*>(hh_s[jl]);
      const float* vb = v_t + ((size_t)(b * NN + j) * 3) * CC + c;
      float v0 = vb[0], v1 = vb[CC], v2 = vb[2 * CC];
      float s0 = 0.f, s1 = 0.f, s2 = 0.f, s3 = 0.f;
#pragma unroll
      for (int k = 0; k < 16; k += 4) {
        float4 hA = hp[k], hB = hp[k + 1], hC = hp[k + 2], hD = hp[k + 3];
        s0 = fmaf(w2r[k].x, hA.x, s0);     s0 = fmaf(w2r[k].y, hA.y, s0);
        s0 = fmaf(w2r[k].z, hA.z, s0);     s0 = fmaf(w2r[k].w, hA.w, s0);
        s1 = fmaf(w2r[k+1].x, hB.x, s1);   s1 = fmaf(w2r[k+1].y, hB.y, s1);
        s1 = fmaf(w2r[k+1].z, hB.z, s1);   s1 = fmaf(w2r[k+1].w, hB.w, s1);
        s2 = fmaf(w2r[k+2].x, hC.x, s2);   s2 = fmaf(w2r[k+2].y, hC.y, s2);
        s2 = fmaf(w2r[k+2].z, hC.z, s2);   s2 = fmaf(w2r[k+2].w, hC.w, s2);
        s3 = fmaf(w2r[k+3].x, hD.x, s3);   s3 = fmaf(w2r[k+3].y, hD.y, s3);
        s3 = fmaf(w2r[k+3].z, hD.z, s3);   s3 = fmaf(w2r[k+3].w, hD.w, s3);
      }
      float s = ((s0 + s1) + (s2 + s3)) + b2c;
      float mn = fmaxf(m, s);
      float p = __expf(s - mn);
      float corr = __expf(m - mn);
      l = fmaf(l, corr, p);
      a0 = fmaf(a0, corr, p * v0);
      a1 = fmaf(a1, corr, p * v1);
      a2 = fmaf(a2, corr, p * v2);
      m = mn;
    }
    __syncthreads();
  }

  // ---- merge the 4 j-quarters per channel (mrg aliases hh_s) ----
  if (par != 0) {
    float* mp = mrg + (cl * 3 + (par - 1)) * 5;
    mp[0] = m; mp[1] = l; mp[2] = a0; mp[3] = a1; mp[4] = a2;
  }
  __syncthreads();
  if (par == 0) {
    float M = m, L = l, A0 = a0, A1 = a1, A2 = a2;
    for (int q = 0; q < 3; q++) {
      const float* mp = mrg + (cl * 3 + q) * 5;
      float m2 = mp[0], l2 = mp[1];
      float mn = fmaxf(M, m2);
      float e1 = __expf(M - mn), e2 = __expf(m2 - mn);
      L = L * e1 + l2 * e2;
      A0 = A0 * e1 + mp[2] * e2;
      A1 = A1 * e1 + mp[3] * e2;
      A2 = A2 * e1 + mp[4] * e2;
      M = mn;
    }
    float inv = 1.f / L;
    float* ap = a_nat + (size_t)(b * CC + c) * COLS + i;
    ap[0] = A0 * inv; ap[256] = A1 * inv; ap[512] = A2 * inv;
  }
}

// ---------------------------------------------------------------------------
// K3: y1 = x + Wo @ a_nat.  grid (48 col-tiles of 16, 2 co-halves, B), 256 thr.
// ---------------------------------------------------------------------------
__global__ __launch_bounds__(256) void k_wo_res(
    const float* __restrict__ a_nat, const float* __restrict__ Wo,
    const float* __restrict__ x, float* __restrict__ y1)
{
  const int ct = blockIdx.x, cohalf = blockIdx.y, b = blockIdx.z;
  const int col0 = ct * 16;
  __shared__ float at[CC][16];
  const float* ab = a_nat + (size_t)b * CC * COLS;
  for (int idx = threadIdx.x; idx < CC * 16; idx += 256) {
    int r = idx >> 4, cc = idx & 15;
    at[r][cc] = ab[r * COLS + col0 + cc];
  }
  __syncthreads();
  const int co = cohalf * 64 + (threadIdx.x >> 2);
  const int cc0 = (threadIdx.x & 3) * 4;
  float acc[4];
#pragma unroll
  for (int k = 0; k < 4; k++) acc[k] = 0.f;
  const float* wrow = Wo + co * CC;
  for (int ci = 0; ci < CC; ci++) {
    float wv = wrow[ci];
#pragma unroll
    for (int k = 0; k < 4; k++) acc[k] = fmaf(wv, at[ci][cc0 + k], acc[k]);
  }
  const size_t base = (size_t)(b * CC + co) * COLS + col0 + cc0;
#pragma unroll
  for (int k = 0; k < 4; k++) y1[base + k] = x[base + k] + acc[k];
}

// ---------------------------------------------------------------------------
// K4: partial ZCA stats. grid (32, B), 256 thr; 4 elements/thread.
// partials[(b*32+blk)*9 + k]
// ---------------------------------------------------------------------------
__global__ __launch_bounds__(256) void k_stats1(
    const float* __restrict__ y, float* __restrict__ partials)
{
  const int blk = blockIdx.x, b = blockIdx.y;
  const float* yb = y + (size_t)b * CC * COLS;
  float v9[9];
#pragma unroll
  for (int k = 0; k < 9; k++) v9[k] = 0.f;
#pragma unroll
  for (int e = 0; e < 4; e++) {
    int idx = blk * 1024 + e * 256 + threadIdx.x;
    int cidx = idx >> 8, n = idx & 255;
    const float* row = yb + cidx * COLS + n;
    float v0 = row[0], v1 = row[256], v2 = row[512];
    v9[0] += v0; v9[1] += v1; v9[2] += v2;
    v9[3] += v0 * v0; v9[4] += v0 * v1; v9[5] += v0 * v2;
    v9[6] += v1 * v1; v9[7] += v1 * v2; v9[8] += v2 * v2;
  }
#pragma unroll
  for (int off = 32; off >= 1; off >>= 1)
#pragma unroll
    for (int k = 0; k < 9; k++) v9[k] += __shfl_down(v9[k], off);
  __shared__ float red[4][9];
  const int wid = threadIdx.x >> 6, lane = threadIdx.x & 63;
  if (lane == 0)
#pragma unroll
    for (int k = 0; k < 9; k++) red[wid][k] = v9[k];
  __syncthreads();
  if (threadIdx.x == 0) {
#pragma unroll
    for (int k = 0; k < 9; k++)
      partials[(size_t)(b * 32 + blk) * 9 + k] =
          ((red[0][k] + red[1][k]) + (red[2][k] + red[3][k]));
  }
}

// ---------------------------------------------------------------------------
// K5: finalize ZCA: reduce partials, 3x3 Jacobi eigh, whitening matrix.
// grid (B), 64 thr (thread 0 does the work -> deterministic).
// stats[b*12 + 0..2]=mu, +3..11 = Wm row-major.
// ---------------------------------------------------------------------------
__global__ __launch_bounds__(64) void k_zca_fin(
    const float* __restrict__ partials, float* __restrict__ stats)
{
  const int b = blockIdx.x;
  if (threadIdx.x != 0) return;
  float tot[9];
#pragma unroll
  for (int k = 0; k < 9; k++) tot[k] = 0.f;
  for (int p = 0; p < 32; p++)
#pragma unroll
    for (int k = 0; k < 9; k++) tot[k] += partials[(size_t)(b * 32 + p) * 9 + k];
  const float M = (float)(CC * NN);
  float mu0 = tot[0] / M, mu1 = tot[1] / M, mu2 = tot[2] / M;
  float A[3][3];
  A[0][0] = (tot[3] - M * mu0 * mu0) / M + 1e-5f;
  A[0][1] = A[1][0] = (tot[4] - M * mu0 * mu1) / M;
  A[0][2] = A[2][0] = (tot[5] - M * mu0 * mu2) / M;
  A[1][1] = (tot[6] - M * mu1 * mu1) / M + 1e-5f;
  A[1][2] = A[2][1] = (tot[7] - M * mu1 * mu2) / M;
  A[2][2] = (tot[8] - M * mu2 * mu2) / M + 1e-5f;
  float V[3][3] = {{1.f, 0.f, 0.f}, {0.f, 1.f, 0.f}, {0.f, 0.f, 1.f}};
  for (int sweep = 0; sweep < 10; sweep++) {
    for (int pi = 0; pi < 3; pi++) {
      const int p = (pi == 2) ? 1 : 0;
      const int q = (pi == 0) ? 1 : 2;
      float apq = A[p][q];
      if (fabsf(apq) < 1e-30f) continue;
      float theta = (A[q][q] - A[p][p]) / (2.f * apq);
      float tt = 1.f / (fabsf(theta) + sqrtf(theta * theta + 1.f));
      if (theta < 0.f) tt = -tt;
      float cr = 1.f / sqrtf(tt * tt + 1.f);
      float sr = tt * cr;
      float app = A[p][p], aqq = A[q][q];
      A[p][p] = app - tt * apq;
      A[q][q] = aqq + tt * apq;
      A[p][q] = A[q][p] = 0.f;
      const int r = 3 - p - q;
      float arp = A[r][p], arq = A[r][q];
      A[r][p] = A[p][r] = cr * arp - sr * arq;
      A[r][q] = A[q][r] = sr * arp + cr * arq;
      for (int rr = 0; rr < 3; rr++) {
        float vrp = V[rr][p], vrq = V[rr][q];
        V[rr][p] = cr * vrp - sr * vrq;
        V[rr][q] = sr * vrp + cr * vrq;
      }
    }
  }
  float rs[3];
#pragma unroll
  for (int k = 0; k < 3; k++) rs[k] = rsqrtf(fmaxf(A[k][k], 1e-5f));
  float* st = stats + b * 12;
  st[0] = mu0; st[1] = mu1; st[2] = mu2;
  for (int u = 0; u < 3; u++)
    for (int v = 0; v < 3; v++) {
      float acc = 0.f;
      for (int k = 0; k < 3; k++) acc += V[u][k] * rs[k] * V[v][k];
      st[3 + u * 3 + v] = acc;
    }
}

// ---------------------------------------------------------------------------
// K6: FFN1 with fused whitening on read:
// h = vn_leaky_relu(Wfeat@x1w, Wdir@x1w), x1w = whiten(y1).
// grid (16 n-tiles of 16, 4 co-splits of 64, B), 256 thr.
// ---------------------------------------------------------------------------
__global__ __launch_bounds__(256) void k_ffn1(
    const float* __restrict__ y1, const float* __restrict__ stats,
    const float* __restrict__ gamma, const float* __restrict__ Wfeat,
    const float* __restrict__ Wdir, float* __restrict__ hout)
{
  const int nt = blockIdx.x, cs = blockIdx.y, b = blockIdx.z;
  const int n0 = nt * 16, co0 = cs * 64;
  __shared__ float xt[CC][48];  // [ci][v*16+nn], whitened
  const float* yb = y1 + (size_t)b * CC * COLS;
  const float* st = stats + b * 12;
  for (int idx = threadIdx.x; idx < CC * 16; idx += 256) {
    int ci = idx >> 4, nn = idx & 15;
    const float* row = yb + ci * COLS + n0 + nn;
    float d0 = row[0] - st[0], d1 = row[256] - st[1], d2 = row[512] - st[2];
    float g = gamma[ci];
    xt[ci][nn]      = g * (st[3] * d0 + st[4] * d1 + st[5] * d2);
    xt[ci][16 + nn] = g * (st[6] * d0 + st[7] * d1 + st[8] * d2);
    xt[ci][32 + nn] = g * (st[9] * d0 + st[10] * d1 + st[11] * d2);
  }
  __syncthreads();
  const int co = co0 + (threadIdx.x & 63);
  const int nn0 = (threadIdx.x >> 6) * 4;
  float p[3][4], d[3][4];
#pragma unroll
  for (int v = 0; v < 3; v++)
#pragma unroll
    for (int k = 0; k < 4; k++) { p[v][k] = 0.f; d[v][k] = 0.f; }
  const float* wf = Wfeat + co * CC;
  const float* wd = Wdir + co * CC;
  for (int ci = 0; ci < CC; ci++) {
    float a = wf[ci], bb = wd[ci];
#pragma unroll
    for (int v = 0; v < 3; v++)
#pragma unroll
      for (int k = 0; k < 4; k++) {
        float xv = xt[ci][v * 16 + nn0 + k];
        p[v][k] = fmaf(a, xv, p[v][k]);
        d[v][k] = fmaf(bb, xv, d[v][k]);
      }
  }
  float* hb = hout + (size_t)(b * CHX + co) * COLS;
#pragma unroll
  for (int k = 0; k < 4; k++) {
    float dot = p[0][k] * d[0][k] + p[1][k] * d[1][k] + p[2][k] * d[2][k];
    float dsq = d[0][k] * d[0][k] + d[1][k] * d[1][k] + d[2][k] * d[2][k];
    float coef = (dot >= 0.f) ? 0.f : (1.f - NEG_FFN) * dot / (dsq + 1e-6f);
#pragma unroll
    for (int v = 0; v < 3; v++)
      hb[v * 256 + n0 + nn0 + k] = p[v][k] - coef * d[v][k];
  }
}

// ---------------------------------------------------------------------------
// K7: x2 = whiten(y1) + Wffn2 @ h.  grid (48 col-tiles of 16, 2 co-halves, B).
// ---------------------------------------------------------------------------
__global__ __launch_bounds__(256) void k_ffn2(
    const float* __restrict__ h, const float* __restrict__ Wffn2,
    const float* __restrict__ y1, const float* __restrict__ stats,
    const float* __restrict__ gamma, float* __restrict__ x2)
{
  const int ct = blockIdx.x, cohalf = blockIdx.y, b = blockIdx.z;
  const int col0 = ct * 16;
  __shared__ float ht[CHX][16];
  const float* hb = h + (size_t)b * CHX * COLS;
  for (int idx = threadIdx.x; idx < CHX * 16; idx += 256) {
    int r = idx >> 4, cc = idx & 15;
    ht[r][cc] = hb[r * COLS + col0 + cc];
  }
  __syncthreads();
  const int co = cohalf * 64 + (threadIdx.x >> 2);
  const int cc0 = (threadIdx.x & 3) * 4;
  float acc[4];
#pragma unroll
  for (int k = 0; k < 4; k++) acc[k] = 0.f;
  const float* w = Wffn2 + co * CHX;
  for (int ci = 0; ci < CHX; ci++) {
    float wv = w[ci];
#pragma unroll
    for (int k = 0; k < 4; k++) acc[k] = fmaf(wv, ht[ci][cc0 + k], acc[k]);
  }
  // residual: whitened x1 component on the fly
  const int col_base = col0 + cc0;
  const int v = col_base >> 8, n = col_base & 255;
  const float* st = stats + b * 12;
  const float* yb = y1 + (size_t)(b * CC + co) * COLS + n;
  const float g = gamma[co];
  const float w0 = st[3 + v * 3 + 0], w1 = st[3 + v * 3 + 1], w2 = st[3 + v * 3 + 2];
  const size_t base = (size_t)(b * CC + co) * COLS + col_base;
#pragma unroll
  for (int k = 0; k < 4; k++) {
    float d0 = yb[k] - st[0], d1 = yb[256 + k] - st[1], d2 = yb[512 + k] - st[2];
    float xw = g * (w0 * d0 + w1 * d1 + w2 * d2);
    x2[base + k] = xw + acc[k];
  }
}

// ---------------------------------------------------------------------------
// K8: final whitening apply -> out. grid (256), 256 thr, 1 element each.
// ---------------------------------------------------------------------------
__global__ __launch_bounds__(256) void k_zca_apply(
    const float* __restrict__ y, const float* __restrict__ stats,
    const float* __restrict__ gamma, float* __restrict__ out)
{
  int idx = blockIdx.x * blockDim.x + threadIdx.x;
  int b = idx >> 15, rem = idx & 32767;
  int cidx = rem >> 8, n = rem & 255;
  const float* st = stats + b * 12;
  const size_t base = (size_t)(b * CC + cidx) * COLS + n;
  float v0 = y[base] - st[0];
  float v1 = y[base + 256] - st[1];
  float v2 = y[base + 512] - st[2];
  float g = gamma[cidx];
  out[base]       = g * (st[3] * v0 + st[4] * v1 + st[5] * v2);
  out[base + 256] = g * (st[6] * v0 + st[7] * v1 + st[8] * v2);
  out[base + 512] = g * (st[9] * v0 + st[10] * v1 + st[11] * v2);
}

// ---------------------------------------------------------------------------
extern "C" void kernel_launch(void* const* d_in, const int* in_sizes, int n_in,
                              void* d_out, int out_size, void* d_ws, size_t ws_size,
                              hipStream_t stream)
{
  (void)in_sizes; (void)n_in; (void)out_size; (void)ws_size;
  const float* x      = (const float*)d_in[0];
  const float* pos    = (const float*)d_in[1];
  const float* Wq     = (const float*)d_in[2];
  const float* Wk     = (const float*)d_in[3];
  const float* Wv     = (const float*)d_in[4];
  const float* Wo     = (const float*)d_in[5];
  const float* W1     = (const float*)d_in[6];
  const float* b1     = (const float*)d_in[7];
  const float* W2     = (const float*)d_in[8];
  const float* b2     = (const float*)d_in[9];
  const float* gamma1 = (const float*)d_in[10];
  const float* Wfeat  = (const float*)d_in[11];
  const float* Wdir   = (const float*)d_in[12];
  const float* Wffn2  = (const float*)d_in[13];
  const float* gamma2 = (const float*)d_in[14];

  float* ws = (float*)d_ws;
  const size_t SZ = (size_t)BB * CC * 3 * NN;  // 393216 floats
  float* q_t   = ws;            // [0, SZ)
  float* k_nat = ws + SZ;       // [SZ, 2SZ)
  float* v_t   = ws + 2 * SZ;   // [2SZ, 3SZ)
  float* a_nat = ws + 3 * SZ;   // [3SZ, 4SZ)
  float* y1    = ws;            // alias q_t   (q_t dead after k_attn)
  float* part1 = ws + 2 * SZ;   // alias v_t   (v_t dead after k_attn), 576 floats
  float* hbuf  = ws + 2 * SZ;   // [2SZ, 4SZ)  (part1+a_nat dead by then)
  float* x2    = ws + SZ;       // alias k_nat (dead after k_attn)
  float* part2 = ws + 2 * SZ;   // alias hbuf  (dead after k_ffn2)
  float* stats1 = ws + 4 * SZ;       // 24 floats
  float* stats2 = ws + 4 * SZ + 24;  // 24 floats

  k_qkv<<<dim3(48, 3, BB), 256, 0, stream>>>(x, Wq, Wk, Wv, q_t, k_nat, v_t);
  k_attn<<<dim3(NN, 2, BB), 256, 0, stream>>>(q_t, k_nat, v_t, pos, W1, b1, W2, b2, a_nat);
  k_wo_res<<<dim3(48, 2, BB), 256, 0, stream>>>(a_nat, Wo, x, y1);
  k_stats1<<<dim3(32, BB), 256, 0, stream>>>(y1, part1);
  k_zca_fin<<<BB, 64, 0, stream>>>(part1, stats1);
  k_ffn1<<<dim3(16, 4, BB), 256, 0, stream>>>(y1, stats1, gamma1, Wfeat, Wdir, hbuf);
  k_ffn2<<<dim3(48, 2, BB), 256, 0, stream>>>(hbuf, Wffn2, y1, stats1, gamma1, x2);
  k_stats1<<<dim3(32, BB), 256, 0, stream>>>(x2, part2);
  k_zca_fin<<<BB, 64, 0, stream>>>(part2, stats2);
  k_zca_apply<<<256, 256, 0, stream>>>(x2, stats2, gamma2, (float*)d_out);
}

// Round 3
// 113.433 us; speedup vs baseline: 1.9042x; 1.3266x over previous
//
#include <hip/hip_runtime.h>
#include <math.h>

// Problem constants (B=2, C=128, N=256, H=64, CH=256)
#define BB 2
#define CC 128
#define NN 256
#define HH 64
#define CHX 256
#define COLS 768           // 3*N flattened (v,n) columns
#define NEG_ATTN 0.2f
#define NEG_FFN 0.1f

typedef __attribute__((ext_vector_type(8))) short short8b;   // 8 bf16 (4 VGPRs)
typedef __attribute__((ext_vector_type(4))) float f32x4;

__device__ __forceinline__ unsigned bf16rne(float x) {
  unsigned u = __float_as_uint(x);
  return (u + 0x7fffu + ((u >> 16) & 1u)) >> 16;
}

// ---------------------------------------------------------------------------
// K1: q,k,v = Wq/Wk/Wv @ x in three layouts.
// grid (48 col-tiles of 16, 3 which, B), 256 threads
// ---------------------------------------------------------------------------
__global__ __launch_bounds__(256) void k_qkv(
    const float* __restrict__ x, const float* __restrict__ Wq,
    const float* __restrict__ Wk, const float* __restrict__ Wv,
    float* __restrict__ q_t, float* __restrict__ k_nat, float* __restrict__ v_t)
{
  const int ct = blockIdx.x, which = blockIdx.y, b = blockIdx.z;
  const int col0 = ct * 16;
  __shared__ float xt[CC][16];
  const float* xb = x + (size_t)b * CC * COLS;
  for (int idx = threadIdx.x; idx < CC * 16; idx += 256) {
    int r = idx >> 4, cc = idx & 15;
    xt[r][cc] = xb[r * COLS + col0 + cc];
  }
  __syncthreads();
  const float* W = (which == 0) ? Wq : ((which == 1) ? Wk : Wv);
  const int co = threadIdx.x >> 1;
  const int cc0 = (threadIdx.x & 1) * 8;
  float acc[8];
#pragma unroll
  for (int k = 0; k < 8; k++) acc[k] = 0.f;
  const float* wrow = W + co * CC;
  for (int ci = 0; ci < CC; ci++) {
    float wv = wrow[ci];
#pragma unroll
    for (int k = 0; k < 8; k++) acc[k] = fmaf(wv, xt[ci][cc0 + k], acc[k]);
  }
#pragma unroll
  for (int k = 0; k < 8; k++) {
    int col = col0 + cc0 + k;
    int v = col >> 8, n = col & 255;
    float val = acc[k];
    if (which == 0)      q_t[((size_t)(b * NN + n) * CC + co) * 3 + v] = val;
    else if (which == 1) k_nat[(size_t)(b * CC + co) * COLS + col] = val;
    else                 v_t[((size_t)(b * NN + n) * 3 + v) * CC + co] = val;
  }
}

// ---------------------------------------------------------------------------
// K1b: rel norms, computed once: rm_all[b][i][j], rp_all[b][i][j].
// grid (N/2, B), 256 threads (thread = j, 2 i's per block for k-reuse).
// ---------------------------------------------------------------------------
__global__ __launch_bounds__(256) void k_rel(
    const float* __restrict__ q_t, const float* __restrict__ k_nat,
    const float* __restrict__ pos, float* __restrict__ rm_all,
    float* __restrict__ rp_all)
{
  const int i0 = blockIdx.x * 2, b = blockIdx.y;
  const int t = threadIdx.x;
  __shared__ float qv[2 * CC * 3];
  for (int idx = t; idx < 2 * CC * 3; idx += 256)
    qv[idx] = q_t[(size_t)(b * NN + i0) * CC * 3 + idx];
  __syncthreads();
  const int j = t;
  const float* kb = k_nat + (size_t)b * CC * COLS;
  float a00 = 0.f, a01 = 0.f, a10 = 0.f, a11 = 0.f;
  for (int c = 0; c < CC; c += 2) {
    float kx0 = kb[c * COLS + j], ky0 = kb[c * COLS + 256 + j], kz0 = kb[c * COLS + 512 + j];
    float kx1 = kb[(c + 1) * COLS + j], ky1 = kb[(c + 1) * COLS + 256 + j], kz1 = kb[(c + 1) * COLS + 512 + j];
    {
      float dx = kx0 - qv[c * 3], dy = ky0 - qv[c * 3 + 1], dz = kz0 - qv[c * 3 + 2];
      float sq = dx * dx + dy * dy + dz * dz;
      a00 += (sq > 0.f) ? sqrtf(sq) : 0.f;
      dx = kx1 - qv[(c + 1) * 3]; dy = ky1 - qv[(c + 1) * 3 + 1]; dz = kz1 - qv[(c + 1) * 3 + 2];
      sq = dx * dx + dy * dy + dz * dz;
      a01 += (sq > 0.f) ? sqrtf(sq) : 0.f;
    }
    {
      const float* q1 = qv + CC * 3;
      float dx = kx0 - q1[c * 3], dy = ky0 - q1[c * 3 + 1], dz = kz0 - q1[c * 3 + 2];
      float sq = dx * dx + dy * dy + dz * dz;
      a10 += (sq > 0.f) ? sqrtf(sq) : 0.f;
      dx = kx1 - q1[(c + 1) * 3]; dy = ky1 - q1[(c + 1) * 3 + 1]; dz = kz1 - q1[(c + 1) * 3 + 2];
      sq = dx * dx + dy * dy + dz * dz;
      a11 += (sq > 0.f) ? sqrtf(sq) : 0.f;
    }
  }
  rm_all[(size_t)(b * NN + i0) * NN + j]     = (a00 + a01) * (1.f / 128.f);
  rm_all[(size_t)(b * NN + i0 + 1) * NN + j] = (a10 + a11) * (1.f / 128.f);
  float pjx = pos[(b * NN + j) * 3], pjy = pos[(b * NN + j) * 3 + 1], pjz = pos[(b * NN + j) * 3 + 2];
#pragma unroll
  for (int ii = 0; ii < 2; ii++) {
    float dx = pos[(b * NN + i0 + ii) * 3] - pjx;
    float dy = pos[(b * NN + i0 + ii) * 3 + 1] - pjy;
    float dz = pos[(b * NN + i0 + ii) * 3 + 2] - pjz;
    float sq = dx * dx + dy * dy + dz * dz;
    rp_all[(size_t)(b * NN + i0 + ii) * NN + j] = (sq > 0.f) ? sqrtf(sq) : 0.f;
  }
}

// ---------------------------------------------------------------------------
// K2: fused attention per (b, i, c-half). grid (N, 2, B), 256 threads.
// Score MLP contraction via bf16 MFMA (16x16x32), scores fp32 in LDS,
// per-c-thread online softmax + PV. b2 dropped (softmax shift-invariant).
// ---------------------------------------------------------------------------
__global__ __launch_bounds__(256, 4) void k_attn(
    const float* __restrict__ rm_all, const float* __restrict__ rp_all,
    const float* __restrict__ v_t, const float* __restrict__ W1,
    const float* __restrict__ b1, const float* __restrict__ W2,
    float* __restrict__ a_nat)
{
  const int i = blockIdx.x, chalf = blockIdx.y, b = blockIdx.z;
  const int t = threadIdx.x;
  __shared__ __align__(16) short hh_s[64 * 64];   // bf16 bits, XOR-swizzled
  __shared__ __align__(16) short w2_s[64 * 64];   // bf16 bits, XOR-swizzled
  __shared__ float sc_s[64 * 65];                 // fp32 scores (padded stride)
  __shared__ float rm_s[NN], rp_s[NN];

  // ---- setup: rm/rp row + W2 half -> bf16 swizzled LDS ----
  rm_s[t] = rm_all[(size_t)(b * NN + i) * NN + t];
  rp_s[t] = rp_all[(size_t)(b * NN + i) * NN + t];
  {
    const int cl = t >> 2, h0 = (t & 3) * 16;
    const float* wrow = W2 + (size_t)(chalf * 64 + cl) * HH + h0;
#pragma unroll
    for (int e = 0; e < 8; e++) {
      unsigned lo = bf16rne(wrow[2 * e]);
      unsigned hi = bf16rne(wrow[2 * e + 1]);
      int didx = (cl * 32 + (h0 >> 1) + e) ^ ((cl & 7) << 2);
      ((unsigned*)w2_s)[didx] = lo | (hi << 16);
    }
  }
  // phase-2 weights for this thread (h-pair h2, h2+1; j-group jgrp)
  const int h2 = (t & 31) * 2, jgrp = t >> 5;
  const float4 w1v = *reinterpret_cast<const float4*>(W1 + 2 * h2);
  const float c0 = b1[h2], c1 = b1[h2 + 1];
  __syncthreads();

  auto phase2 = [&](int q) {
#pragma unroll
    for (int jj = 0; jj < 8; jj++) {
      int jl = jgrp * 8 + jj;
      int jg = q * 64 + jl;
      float rmv = rm_s[jg], rpv = rp_s[jg];
      float g0 = fmaf(w1v.x, rmv, fmaf(w1v.y, rpv, c0));
      float g1 = fmaf(w1v.z, rmv, fmaf(w1v.w, rpv, c1));
      g0 = (g0 >= 0.f) ? g0 : NEG_ATTN * g0;
      g1 = (g1 >= 0.f) ? g1 : NEG_ATTN * g1;
      int didx = (jl * 32 + (h2 >> 1)) ^ ((jl & 7) << 2);
      ((unsigned*)hh_s)[didx] = bf16rne(g0) | (bf16rne(g1) << 16);
    }
  };

  phase2(0);
  __syncthreads();

  const int lane = t & 63, wv = t >> 6;
  const int g8 = (lane >> 4) * 8;
  // B-frags for this wave's c-tile (loop-invariant, 16 VGPRs total)
  const int cdx = wv * 16 + (lane & 15);
  const short8b bfr0 = *reinterpret_cast<const short8b*>(&w2_s[(cdx * 64 + g8) ^ ((cdx & 7) << 3)]);
  const short8b bfr1 = *reinterpret_cast<const short8b*>(&w2_s[(cdx * 64 + 32 + g8) ^ ((cdx & 7) << 3)]);

  const int cl = lane;               // PV channel within half
  const int par = wv;                // j stride-4 offset (wave-uniform)
  const int vc = chalf * 64 + cl;
  float m = -1e30f, l = 0.f, a0 = 0.f, a1 = 0.f, a2 = 0.f;

  for (int q = 0; q < 4; q++) {
    // ---- MFMA: wave wv = c-tile wv, 4 j-tiles, K=64 in 2 steps ----
#pragma unroll
    for (int jt = 0; jt < 4; jt++) {
      int jr = jt * 16 + (lane & 15);
      short8b af0 = *reinterpret_cast<const short8b*>(&hh_s[(jr * 64 + g8) ^ ((jr & 7) << 3)]);
      short8b af1 = *reinterpret_cast<const short8b*>(&hh_s[(jr * 64 + 32 + g8) ^ ((jr & 7) << 3)]);
      f32x4 acc = {0.f, 0.f, 0.f, 0.f};
      acc = __builtin_amdgcn_mfma_f32_16x16x32_bf16(af0, bfr0, acc, 0, 0, 0);
      acc = __builtin_amdgcn_mfma_f32_16x16x32_bf16(af1, bfr1, acc, 0, 0, 0);
      int row0 = jt * 16 + (lane >> 4) * 4;
      int ccol = wv * 16 + (lane & 15);
#pragma unroll
      for (int r = 0; r < 4; r++) sc_s[(row0 + r) * 65 + ccol] = acc[r];
    }
    __syncthreads();
    // ---- PV: online softmax per (c, par), 16 j each ----
#pragma unroll
    for (int jj = 0; jj < 16; jj++) {
      int jl = jj * 4 + par;
      int jg = q * 64 + jl;
      float s = sc_s[jl * 65 + cl];
      const float* vb = v_t + ((size_t)(b * NN + jg) * 3) * CC + vc;
      float v0 = vb[0], v1 = vb[CC], v2 = vb[2 * CC];
      float mn = fmaxf(m, s);
      float p = __expf(s - mn);
      float corr = __expf(m - mn);
      l = fmaf(l, corr, p);
      a0 = fmaf(a0, corr, p * v0);
      a1 = fmaf(a1, corr, p * v1);
      a2 = fmaf(a2, corr, p * v2);
      m = mn;
    }
    if (q < 3) phase2(q + 1);
    __syncthreads();
  }

  // ---- merge the 4 j-parities per channel (mrg aliases sc_s) ----
  float* mrg = sc_s;
  if (par != 0) {
    float* mp = mrg + (cl * 3 + (par - 1)) * 5;
    mp[0] = m; mp[1] = l; mp[2] = a0; mp[3] = a1; mp[4] = a2;
  }
  __syncthreads();
  if (par == 0) {
    float M = m, L = l, A0 = a0, A1 = a1, A2 = a2;
    for (int q = 0; q < 3; q++) {
      const float* mp = mrg + (cl * 3 + q) * 5;
      float m2 = mp[0], l2 = mp[1];
      float mn = fmaxf(M, m2);
      float e1 = __expf(M - mn), e2 = __expf(m2 - mn);
      L = L * e1 + l2 * e2;
      A0 = A0 * e1 + mp[2] * e2;
      A1 = A1 * e1 + mp[3] * e2;
      A2 = A2 * e1 + mp[4] * e2;
      M = mn;
    }
    float inv = 1.f / L;
    float* ap = a_nat + (size_t)(b * CC + vc) * COLS + i;
    ap[0] = A0 * inv; ap[256] = A1 * inv; ap[512] = A2 * inv;
  }
}

// ---------------------------------------------------------------------------
// K3: y1 = x + Wo @ a_nat.  grid (48 col-tiles of 16, 2 co-halves, B), 256 thr.
// ---------------------------------------------------------------------------
__global__ __launch_bounds__(256) void k_wo_res(
    const float* __restrict__ a_nat, const float* __restrict__ Wo,
    const float* __restrict__ x, float* __restrict__ y1)
{
  const int ct = blockIdx.x, cohalf = blockIdx.y, b = blockIdx.z;
  const int col0 = ct * 16;
  __shared__ float at[CC][16];
  const float* ab = a_nat + (size_t)b * CC * COLS;
  for (int idx = threadIdx.x; idx < CC * 16; idx += 256) {
    int r = idx >> 4, cc = idx & 15;
    at[r][cc] = ab[r * COLS + col0 + cc];
  }
  __syncthreads();
  const int co = cohalf * 64 + (threadIdx.x >> 2);
  const int cc0 = (threadIdx.x & 3) * 4;
  float acc[4];
#pragma unroll
  for (int k = 0; k < 4; k++) acc[k] = 0.f;
  const float* wrow = Wo + co * CC;
  for (int ci = 0; ci < CC; ci++) {
    float wv = wrow[ci];
#pragma unroll
    for (int k = 0; k < 4; k++) acc[k] = fmaf(wv, at[ci][cc0 + k], acc[k]);
  }
  const size_t base = (size_t)(b * CC + co) * COLS + col0 + cc0;
#pragma unroll
  for (int k = 0; k < 4; k++) y1[base + k] = x[base + k] + acc[k];
}

// ---------------------------------------------------------------------------
// K4: partial ZCA stats. grid (32, B), 256 thr; 4 elements/thread.
// ---------------------------------------------------------------------------
__global__ __launch_bounds__(256) void k_stats1(
    const float* __restrict__ y, float* __restrict__ partials)
{
  const int blk = blockIdx.x, b = blockIdx.y;
  const float* yb = y + (size_t)b * CC * COLS;
  float v9[9];
#pragma unroll
  for (int k = 0; k < 9; k++) v9[k] = 0.f;
#pragma unroll
  for (int e = 0; e < 4; e++) {
    int idx = blk * 1024 + e * 256 + threadIdx.x;
    int cidx = idx >> 8, n = idx & 255;
    const float* row = yb + cidx * COLS + n;
    float v0 = row[0], v1 = row[256], v2 = row[512];
    v9[0] += v0; v9[1] += v1; v9[2] += v2;
    v9[3] += v0 * v0; v9[4] += v0 * v1; v9[5] += v0 * v2;
    v9[6] += v1 * v1; v9[7] += v1 * v2; v9[8] += v2 * v2;
  }
#pragma unroll
  for (int off = 32; off >= 1; off >>= 1)
#pragma unroll
    for (int k = 0; k < 9; k++) v9[k] += __shfl_down(v9[k], off);
  __shared__ float red[4][9];
  const int wid = threadIdx.x >> 6, lane = threadIdx.x & 63;
  if (lane == 0)
#pragma unroll
    for (int k = 0; k < 9; k++) red[wid][k] = v9[k];
  __syncthreads();
  if (threadIdx.x == 0) {
#pragma unroll
    for (int k = 0; k < 9; k++)
      partials[(size_t)(b * 32 + blk) * 9 + k] =
          ((red[0][k] + red[1][k]) + (red[2][k] + red[3][k]));
  }
}

// ---------------------------------------------------------------------------
// K5: finalize ZCA: reduce partials, 3x3 Jacobi eigh, whitening matrix.
// ---------------------------------------------------------------------------
__global__ __launch_bounds__(64) void k_zca_fin(
    const float* __restrict__ partials, float* __restrict__ stats)
{
  const int b = blockIdx.x;
  if (threadIdx.x != 0) return;
  float tot[9];
#pragma unroll
  for (int k = 0; k < 9; k++) tot[k] = 0.f;
  for (int p = 0; p < 32; p++)
#pragma unroll
    for (int k = 0; k < 9; k++) tot[k] += partials[(size_t)(b * 32 + p) * 9 + k];
  const float M = (float)(CC * NN);
  float mu0 = tot[0] / M, mu1 = tot[1] / M, mu2 = tot[2] / M;
  float A[3][3];
  A[0][0] = (tot[3] - M * mu0 * mu0) / M + 1e-5f;
  A[0][1] = A[1][0] = (tot[4] - M * mu0 * mu1) / M;
  A[0][2] = A[2][0] = (tot[5] - M * mu0 * mu2) / M;
  A[1][1] = (tot[6] - M * mu1 * mu1) / M + 1e-5f;
  A[1][2] = A[2][1] = (tot[7] - M * mu1 * mu2) / M;
  A[2][2] = (tot[8] - M * mu2 * mu2) / M + 1e-5f;
  float V[3][3] = {{1.f, 0.f, 0.f}, {0.f, 1.f, 0.f}, {0.f, 0.f, 1.f}};
  for (int sweep = 0; sweep < 10; sweep++) {
    for (int pi = 0; pi < 3; pi++) {
      const int p = (pi == 2) ? 1 : 0;
      const int q = (pi == 0) ? 1 : 2;
      float apq = A[p][q];
      if (fabsf(apq) < 1e-30f) continue;
      float theta = (A[q][q] - A[p][p]) / (2.f * apq);
      float tt = 1.f / (fabsf(theta) + sqrtf(theta * theta + 1.f));
      if (theta < 0.f) tt = -tt;
      float cr = 1.f / sqrtf(tt * tt + 1.f);
      float sr = tt * cr;
      float app = A[p][p], aqq = A[q][q];
      A[p][p] = app - tt * apq;
      A[q][q] = aqq + tt * apq;
      A[p][q] = A[q][p] = 0.f;
      const int r = 3 - p - q;
      float arp = A[r][p], arq = A[r][q];
      A[r][p] = A[p][r] = cr * arp - sr * arq;
      A[r][q] = A[q][r] = sr * arp + cr * arq;
      for (int rr = 0; rr < 3; rr++) {
        float vrp = V[rr][p], vrq = V[rr][q];
        V[rr][p] = cr * vrp - sr * vrq;
        V[rr][q] = sr * vrp + cr * vrq;
      }
    }
  }
  float rs[3];
#pragma unroll
  for (int k = 0; k < 3; k++) rs[k] = rsqrtf(fmaxf(A[k][k], 1e-5f));
  float* st = stats + b * 12;
  st[0] = mu0; st[1] = mu1; st[2] = mu2;
  for (int u = 0; u < 3; u++)
    for (int v = 0; v < 3; v++) {
      float acc = 0.f;
      for (int k = 0; k < 3; k++) acc += V[u][k] * rs[k] * V[v][k];
      st[3 + u * 3 + v] = acc;
    }
}

// ---------------------------------------------------------------------------
// K6: FFN1 with fused whitening on read.
// ---------------------------------------------------------------------------
__global__ __launch_bounds__(256) void k_ffn1(
    const float* __restrict__ y1, const float* __restrict__ stats,
    const float* __restrict__ gamma, const float* __restrict__ Wfeat,
    const float* __restrict__ Wdir, float* __restrict__ hout)
{
  const int nt = blockIdx.x, cs = blockIdx.y, b = blockIdx.z;
  const int n0 = nt * 16, co0 = cs * 64;
  __shared__ float xt[CC][48];
  const float* yb = y1 + (size_t)b * CC * COLS;
  const float* st = stats + b * 12;
  for (int idx = threadIdx.x; idx < CC * 16; idx += 256) {
    int ci = idx >> 4, nn = idx & 15;
    const float* row = yb + ci * COLS + n0 + nn;
    float d0 = row[0] - st[0], d1 = row[256] - st[1], d2 = row[512] - st[2];
    float g = gamma[ci];
    xt[ci][nn]      = g * (st[3] * d0 + st[4] * d1 + st[5] * d2);
    xt[ci][16 + nn] = g * (st[6] * d0 + st[7] * d1 + st[8] * d2);
    xt[ci][32 + nn] = g * (st[9] * d0 + st[10] * d1 + st[11] * d2);
  }
  __syncthreads();
  const int co = co0 + (threadIdx.x & 63);
  const int nn0 = (threadIdx.x >> 6) * 4;
  float p[3][4], d[3][4];
#pragma unroll
  for (int v = 0; v < 3; v++)
#pragma unroll
    for (int k = 0; k < 4; k++) { p[v][k] = 0.f; d[v][k] = 0.f; }
  const float* wf = Wfeat + co * CC;
  const float* wd = Wdir + co * CC;
  for (int ci = 0; ci < CC; ci++) {
    float a = wf[ci], bb = wd[ci];
#pragma unroll
    for (int v = 0; v < 3; v++)
#pragma unroll
      for (int k = 0; k < 4; k++) {
        float xv = xt[ci][v * 16 + nn0 + k];
        p[v][k] = fmaf(a, xv, p[v][k]);
        d[v][k] = fmaf(bb, xv, d[v][k]);
      }
  }
  float* hb = hout + (size_t)(b * CHX + co) * COLS;
#pragma unroll
  for (int k = 0; k < 4; k++) {
    float dot = p[0][k] * d[0][k] + p[1][k] * d[1][k] + p[2][k] * d[2][k];
    float dsq = d[0][k] * d[0][k] + d[1][k] * d[1][k] + d[2][k] * d[2][k];
    float coef = (dot >= 0.f) ? 0.f : (1.f - NEG_FFN) * dot / (dsq + 1e-6f);
#pragma unroll
    for (int v = 0; v < 3; v++)
      hb[v * 256 + n0 + nn0 + k] = p[v][k] - coef * d[v][k];
  }
}

// ---------------------------------------------------------------------------
// K7: x2 = whiten(y1) + Wffn2 @ h.
// ---------------------------------------------------------------------------
__global__ __launch_bounds__(256) void k_ffn2(
    const float* __restrict__ h, const float* __restrict__ Wffn2,
    const float* __restrict__ y1, const float* __restrict__ stats,
    const float* __restrict__ gamma, float* __restrict__ x2)
{
  const int ct = blockIdx.x, cohalf = blockIdx.y, b = blockIdx.z;
  const int col0 = ct * 16;
  __shared__ float ht[CHX][16];
  const float* hb = h + (size_t)b * CHX * COLS;
  for (int idx = threadIdx.x; idx < CHX * 16; idx += 256) {
    int r = idx >> 4, cc = idx & 15;
    ht[r][cc] = hb[r * COLS + col0 + cc];
  }
  __syncthreads();
  const int co = cohalf * 64 + (threadIdx.x >> 2);
  const int cc0 = (threadIdx.x & 3) * 4;
  float acc[4];
#pragma unroll
  for (int k = 0; k < 4; k++) acc[k] = 0.f;
  const float* w = Wffn2 + co * CHX;
  for (int ci = 0; ci < CHX; ci++) {
    float wv = w[ci];
#pragma unroll
    for (int k = 0; k < 4; k++) acc[k] = fmaf(wv, ht[ci][cc0 + k], acc[k]);
  }
  const int col_base = col0 + cc0;
  const int v = col_base >> 8, n = col_base & 255;
  const float* st = stats + b * 12;
  const float* yb = y1 + (size_t)(b * CC + co) * COLS + n;
  const float g = gamma[co];
  const float w0 = st[3 + v * 3 + 0], w1 = st[3 + v * 3 + 1], w2 = st[3 + v * 3 + 2];
  const size_t base = (size_t)(b * CC + co) * COLS + col_base;
#pragma unroll
  for (int k = 0; k < 4; k++) {
    float d0 = yb[k] - st[0], d1 = yb[256 + k] - st[1], d2 = yb[512 + k] - st[2];
    float xw = g * (w0 * d0 + w1 * d1 + w2 * d2);
    x2[base + k] = xw + acc[k];
  }
}

// ---------------------------------------------------------------------------
// K8: final whitening apply -> out.
// ---------------------------------------------------------------------------
__global__ __launch_bounds__(256) void k_zca_apply(
    const float* __restrict__ y, const float* __restrict__ stats,
    const float* __restrict__ gamma, float* __restrict__ out)
{
  int idx = blockIdx.x * blockDim.x + threadIdx.x;
  int b = idx >> 15, rem = idx & 32767;
  int cidx = rem >> 8, n = rem & 255;
  const float* st = stats + b * 12;
  const size_t base = (size_t)(b * CC + cidx) * COLS + n;
  float v0 = y[base] - st[0];
  float v1 = y[base + 256] - st[1];
  float v2 = y[base + 512] - st[2];
  float g = gamma[cidx];
  out[base]       = g * (st[3] * v0 + st[4] * v1 + st[5] * v2);
  out[base + 256] = g * (st[6] * v0 + st[7] * v1 + st[8] * v2);
  out[base + 512] = g * (st[9] * v0 + st[10] * v1 + st[11] * v2);
}

// ---------------------------------------------------------------------------
extern "C" void kernel_launch(void* const* d_in, const int* in_sizes, int n_in,
                              void* d_out, int out_size, void* d_ws, size_t ws_size,
                              hipStream_t stream)
{
  (void)in_sizes; (void)n_in; (void)out_size; (void)ws_size;
  const float* x      = (const float*)d_in[0];
  const float* pos    = (const float*)d_in[1];
  const float* Wq     = (const float*)d_in[2];
  const float* Wk     = (const float*)d_in[3];
  const float* Wv     = (const float*)d_in[4];
  const float* Wo     = (const float*)d_in[5];
  const float* W1     = (const float*)d_in[6];
  const float* b1     = (const float*)d_in[7];
  const float* W2     = (const float*)d_in[8];
  // d_in[9] = b2 : dropped (softmax shift-invariant per channel)
  const float* gamma1 = (const float*)d_in[10];
  const float* Wfeat  = (const float*)d_in[11];
  const float* Wdir   = (const float*)d_in[12];
  const float* Wffn2  = (const float*)d_in[13];
  const float* gamma2 = (const float*)d_in[14];

  float* ws = (float*)d_ws;
  const size_t SZ = (size_t)BB * CC * 3 * NN;   // 393216 floats
  const size_t RMSZ = (size_t)BB * NN * NN;     // 131072 floats
  // lifetimes: q_t,k_nat dead after k_rel; v_t,rm,rp dead after k_attn;
  // a_nat dead after k_wo_res; hbuf dead after k_ffn2.
  float* q_t    = ws;                  // [0, SZ)
  float* k_nat  = ws + SZ;             // [SZ, 2SZ)
  float* v_t    = ws + 2 * SZ;         // [2SZ, 3SZ)
  float* rm_all = ws + 3 * SZ;         // [3SZ, 3SZ+RMSZ)
  float* rp_all = ws + 3 * SZ + RMSZ;  // [.., 3SZ+2*RMSZ)  (< 4SZ)
  float* a_nat  = ws;                  // alias q_t
  float* y1     = ws + SZ;             // alias k_nat
  float* hbuf   = ws + 2 * SZ;         // [2SZ, 4SZ)
  float* x2     = ws;                  // alias a_nat
  float* part   = ws + 4 * SZ;         // 576 floats
  float* stats1 = ws + 4 * SZ + 640;   // 24 floats
  float* stats2 = ws + 4 * SZ + 704;   // 24 floats

  k_qkv<<<dim3(48, 3, BB), 256, 0, stream>>>(x, Wq, Wk, Wv, q_t, k_nat, v_t);
  k_rel<<<dim3(NN / 2, BB), 256, 0, stream>>>(q_t, k_nat, pos, rm_all, rp_all);
  k_attn<<<dim3(NN, 2, BB), 256, 0, stream>>>(rm_all, rp_all, v_t, W1, b1, W2, a_nat);
  k_wo_res<<<dim3(48, 2, BB), 256, 0, stream>>>(a_nat, Wo, x, y1);
  k_stats1<<<dim3(32, BB), 256, 0, stream>>>(y1, part);
  k_zca_fin<<<BB, 64, 0, stream>>>(part, stats1);
  k_ffn1<<<dim3(16, 4, BB), 256, 0, stream>>>(y1, stats1, gamma1, Wfeat, Wdir, hbuf);
  k_ffn2<<<dim3(48, 2, BB), 256, 0, stream>>>(hbuf, Wffn2, y1, stats1, gamma1, x2);
  k_stats1<<<dim3(32, BB), 256, 0, stream>>>(x2, part);
  k_zca_fin<<<BB, 64, 0, stream>>>(part, stats2);
  k_zca_apply<<<256, 256, 0, stream>>>(x2, stats2, gamma2, (float*)d_out);
}